// Round 1
// baseline (502.031 us; speedup 1.0000x reference)
//
#include <hip/hip_runtime.h>

typedef unsigned short ushort_t;
typedef unsigned int uint_t;
typedef __bf16 bf16x8 __attribute__((ext_vector_type(8)));
typedef float float4v __attribute__((ext_vector_type(4)));
typedef uint_t uint4v __attribute__((ext_vector_type(4)));

#define EPS 1e-6f

// Workspace layout (bytes)
#define WS_STYLE   0            // 16*512 f32 = 32 KB
#define WS_INVD    32768        // 16*512 f32 = 32 KB
#define WS_WSQ     65536        // 512*512 f32 = 1 MB
#define WS_AW      1114112      // 512*4608 bf16 = 4,718,592 B
#define WS_XP      6291456      // 16*66*66*512 bf16 = 71,368,704 B

__device__ __forceinline__ ushort_t f2bf(float v) {
    union { float f; uint_t u; } c; c.f = v;
    uint_t u = c.u;
    u += 0x7fffu + ((u >> 16) & 1u);   // round-to-nearest-even
    return (ushort_t)(u >> 16);
}

__device__ __forceinline__ void gload_lds16(const void* g, void* l) {
    __builtin_amdgcn_global_load_lds(
        (const __attribute__((address_space(1))) uint_t*)g,
        (__attribute__((address_space(3))) uint_t*)l, 16, 0, 0);
}

// ---------------- P1: style[b][o] = w[b,:] . lw[o,:] + lb[o] ----------------
__global__ void compute_style(const float* __restrict__ w, const float* __restrict__ lw,
                              const float* __restrict__ lb, float* __restrict__ style) {
    int gw = blockIdx.x * 4 + (threadIdx.x >> 6);   // 0..8191
    int lane = threadIdx.x & 63;
    int b = gw >> 9, o = gw & 511;
    float s = 0.f;
#pragma unroll
    for (int j = 0; j < 8; ++j) {
        int d = j * 64 + lane;
        s += w[b * 512 + d] * lw[o * 512 + d];
    }
#pragma unroll
    for (int off = 32; off; off >>= 1) s += __shfl_down(s, off);
    if (lane == 0) style[gw] = s + lb[o];
}

// ------- P2: cast conv weight to bf16 [o][t*512+i]; wsq[o][i] = sum_t cw^2 -------
__global__ void prep_weights(const float* __restrict__ cw, ushort_t* __restrict__ Aw,
                             float* __restrict__ wsq) {
    int id = blockIdx.x * 256 + threadIdx.x;        // o*512 + i
    int o = id >> 9, i = id & 511;
    const float* p = cw + (size_t)id * 9;
    float s = 0.f;
#pragma unroll
    for (int t = 0; t < 9; ++t) {
        float v = p[t];
        s += v * v;
        Aw[(size_t)o * 4608 + t * 512 + i] = f2bf(v);
    }
    wsq[id] = s;
}

// ------- P3: inv_denom[b][o] = rsqrt(sum_i wsq[o][i]*style[b][i]^2 + eps) -------
__global__ void compute_invd(const float* __restrict__ wsq, const float* __restrict__ style,
                             float* __restrict__ invd) {
    int gw = blockIdx.x * 4 + (threadIdx.x >> 6);
    int lane = threadIdx.x & 63;
    int b = gw >> 9, o = gw & 511;
    float s = 0.f;
#pragma unroll
    for (int j = 0; j < 8; ++j) {
        int d = j * 64 + lane;
        float st = style[b * 512 + d];
        s += wsq[o * 512 + d] * st * st;
    }
#pragma unroll
    for (int off = 32; off; off >>= 1) s += __shfl_down(s, off);
    if (lane == 0) invd[gw] = rsqrtf(s + EPS);
}

// ------- P4a: zero the 1-px padding border of Xp (NHWC, 66x66) -------
__global__ void zero_border(ushort_t* __restrict__ Xp) {
    int bp = blockIdx.x;          // 0..259
    int b = blockIdx.y;
    int lane = threadIdx.x;       // 64 lanes x 16 B = 1024 B = 512 ch
    int py, px;
    if (bp < 66)       { py = 0;        px = bp; }
    else if (bp < 132) { py = 65;       px = bp - 66; }
    else if (bp < 196) { py = bp - 131; px = 0; }
    else               { py = bp - 195; px = 65; }
    size_t pix = ((size_t)b * 66 + py) * 66 + px;
    ((uint4v*)(Xp + pix * 512))[lane] = (uint4v){0, 0, 0, 0};
}

// ------- P4b: Xp[b][y+1][x+1][i] = bf16(x[b][i][y][x] * style[b][i]) (NHWC interior) -------
__global__ void modulate_transpose(const float* __restrict__ x, const float* __restrict__ style,
                                   ushort_t* __restrict__ Xp) {
    __shared__ ushort_t tile[64][65];   // [i_local][x]
    int y = blockIdx.x;           // 0..63
    int i0 = blockIdx.y * 64;     // 8 tiles of 64 channels
    int b = blockIdx.z;           // 0..15
    int tid = threadIdx.x;
    int sub = tid >> 6;           // 0..3 (wave)
    int lane = tid & 63;          // x position
#pragma unroll
    for (int pass = 0; pass < 16; ++pass) {
        int ir = pass * 4 + sub;
        float s = style[b * 512 + i0 + ir];
        float v = x[(((size_t)b * 512 + i0 + ir) * 64 + y) * 64 + lane] * s;
        tile[ir][lane] = f2bf(v);
    }
    __syncthreads();
    size_t rowbase = ((size_t)b * 66 + (y + 1)) * 66 + 1;
#pragma unroll
    for (int pass = 0; pass < 2; ++pass) {
        int idx = pass * 256 + tid;
        int xx = idx >> 3;        // 0..63
        int ch8 = idx & 7;        // 8-channel chunk
        ushort_t v[8];
#pragma unroll
        for (int j = 0; j < 8; ++j) v[j] = tile[ch8 * 8 + j][xx];
        *(uint4v*)(Xp + (rowbase + xx) * 512 + i0 + ch8 * 8) = *(uint4v*)v;
    }
}

// ---------------- Main implicit-GEMM conv: per batch M=512, N=4096, K=4608 ----------------
// 256x256 tile, BK=64, 512 threads (8 waves, 2M x 4N), per-wave 128x64 output.
// Double-buffered 128 KB LDS; deep pipeline: stages run 2 K-tiles ahead of compute,
// counted s_waitcnt vmcnt(8) (never 0 in the main loop) keeps next K-tile's
// global_load_lds in flight across both barriers (T3+T4). Per K-tile:
//   vmcnt(8); BAR; ds_read ks0(12xb128); 32 MFMA; ds_read ks1; lgkmcnt(0); BAR;
//   stage kt+2 (8 x global_load_lds, same-parity buffer whose reads just finished);
//   32 MFMA.
// Race-freedom: a stage into buf[p] is issued only after the barrier that follows
// lgkmcnt(0) of that buffer's reads (reads are in VGPRs); vmcnt(8)+barrier at the
// top of each K-tile guarantees the tile about to be read has fully landed.
// LDS rows are 128 B (64 bf16 of K) split into 8 granules of 16 B; granule slot
// XOR-swizzled by (row&7) -> each 16-lane read group hits 8 distinct slots 2-way
// (free). global_load_lds dest stays linear; the SAME involution is applied to the
// per-lane global source granule (rule: both-sides-or-neither).
__global__ __launch_bounds__(512, 2) void conv_gemm(const ushort_t* __restrict__ Aw,
                                                    const ushort_t* __restrict__ Xp,
                                                    const float* __restrict__ invd,
                                                    float* __restrict__ out) {
    __shared__ ushort_t lds[2][32768];   // per buf: A [0,32KB), B [32KB,64KB)

    const int tid  = threadIdx.x;
    const int lane = tid & 63;
    const int wv   = tid >> 6;      // 0..7
    const int wm   = wv >> 2;       // 0..1  (M half)
    const int wn   = wv & 3;        // 0..3  (N quarter)
    const int l15  = lane & 15;
    const int quad = lane >> 4;

    // XCD-aware bijective swizzle (512 blocks = 8 XCD x 64): per-XCD chunk has a
    // fixed o-tile (A-panel 2.36 MB stays L2-resident) x 4 batches x all p-tiles.
    const int bid = blockIdx.x;
    const int lid = (bid & 7) * 64 + (bid >> 3);
    const int pxt = lid & 15;          // p-tile 0..15
    const int b   = (lid >> 4) & 15;   // batch
    const int ot  = lid >> 8;          // o-tile 0..1
    const int o0  = ot * 256;
    const int p0  = pxt * 256;

    // ---- staging addresses: thread tid covers granule q = s*512+tid, s=0..3 ----
    // row = s*64 + (tid>>3); stored slot = tid&7; source granule g = slot ^ (row&7)
    const int tr  = tid >> 3;                           // 0..63
    const int gsw = (((tid & 7) ^ (tr & 7)) << 4);      // source granule byte offset (s-independent)
    const char* Ab = (const char*)Aw;
    const char* Xb = (const char*)Xp;
    const char* aga[4];
    const char* bga[4];
#pragma unroll
    for (int s = 0; s < 4; ++s) {
        int row = s * 64 + tr;                          // 0..255 within tile
        aga[s] = Ab + (size_t)(o0 + row) * 9216 + gsw;
        int py0 = pxt * 4 + s;                          // image row of this stage's pixels
        bga[s] = Xb + ((size_t)(b * 66 + py0) * 66 + tr) * 1024 + gsw;
    }
    const int lds_wv = wv * 1024;                       // wave-uniform byte base within stage

    // ---- read-side (frag) addresses ----
    const int sw0 = ((quad ^ (l15 & 7)) << 4);          // k-slice 0 granule slot
    const int sw1 = (((4 + quad) ^ (l15 & 7)) << 4);    // k-slice 1
    const int aoffs = (wm * 128 + l15) * 128;           // A row byte offset (+ mi*2048)
    const int boffs = 32768 + (wn * 64 + l15) * 128;    // B row byte offset (+ ni*2048)

    float4v acc[8][4] = {};

    auto stage = [&](int kt) {
        const int parity = kt & 1;
        const long aoff = (long)kt * 128;
        const int t = kt >> 3;                          // tap 0..8 (const within K-tile)
        const int dh = t / 3, dw = t - dh * 3;
        const long boff = (long)(dh * 66 + dw) * 1024 + (long)(kt & 7) * 128;
        char* la = (char*)&lds[parity][0]     + lds_wv;
        char* lb = (char*)&lds[parity][16384] + lds_wv;
#pragma unroll
        for (int s = 0; s < 4; ++s) {
            gload_lds16(aga[s] + aoff, la + s * 8192);
            gload_lds16(bga[s] + boff, lb + s * 8192);
        }
    };

    // prologue: fill the pipe 2 K-tiles deep
    stage(0);
    stage(1);

#pragma unroll 1
    for (int kt = 0; kt < 72; ++kt) {
        if (kt < 71) { asm volatile("s_waitcnt vmcnt(8)" ::: "memory"); }
        else         { asm volatile("s_waitcnt vmcnt(0)" ::: "memory"); }
        __builtin_amdgcn_s_barrier();

        const char* base = (const char*)&lds[kt & 1][0];
        bf16x8 a0[8], a1[8], b0[4], b1[4];
#pragma unroll
        for (int mi = 0; mi < 8; ++mi)
            a0[mi] = *(const bf16x8*)(base + aoffs + mi * 2048 + sw0);
#pragma unroll
        for (int ni = 0; ni < 4; ++ni)
            b0[ni] = *(const bf16x8*)(base + boffs + ni * 2048 + sw0);

        __builtin_amdgcn_s_setprio(1);
#pragma unroll
        for (int mi = 0; mi < 8; ++mi)
#pragma unroll
            for (int ni = 0; ni < 4; ++ni)
                acc[mi][ni] = __builtin_amdgcn_mfma_f32_16x16x32_bf16(a0[mi], b0[ni], acc[mi][ni], 0, 0, 0);
        __builtin_amdgcn_s_setprio(0);

#pragma unroll
        for (int mi = 0; mi < 8; ++mi)
            a1[mi] = *(const bf16x8*)(base + aoffs + mi * 2048 + sw1);
#pragma unroll
        for (int ni = 0; ni < 4; ++ni)
            b1[ni] = *(const bf16x8*)(base + boffs + ni * 2048 + sw1);

        asm volatile("s_waitcnt lgkmcnt(0)" ::: "memory");   // ks1 frags in VGPRs
        __builtin_amdgcn_s_barrier();                        // all reads of buf[kt&1] done

        if (kt < 70) stage(kt + 2);                          // overwrite just-freed buffer

        __builtin_amdgcn_s_setprio(1);
#pragma unroll
        for (int mi = 0; mi < 8; ++mi)
#pragma unroll
            for (int ni = 0; ni < 4; ++ni)
                acc[mi][ni] = __builtin_amdgcn_mfma_f32_16x16x32_bf16(a1[mi], b1[ni], acc[mi][ni], 0, 0, 0);
        __builtin_amdgcn_s_setprio(0);
    }

    // epilogue: out[b][o][p] = acc * inv_denom[b][o]
    const float* invb = invd + b * 512 + o0 + wm * 128;
    float* outb = out + ((size_t)b * 512 + o0 + wm * 128) * 4096 + p0 + wn * 64;
#pragma unroll
    for (int mi = 0; mi < 8; ++mi) {
#pragma unroll
        for (int r = 0; r < 4; ++r) {
            int m = mi * 16 + quad * 4 + r;
            float d = invb[m];
#pragma unroll
            for (int ni = 0; ni < 4; ++ni) {
                int n = ni * 16 + l15;
                outb[(size_t)m * 4096 + n] = acc[mi][ni][r] * d;
            }
        }
    }
}

extern "C" void kernel_launch(void* const* d_in, const int* in_sizes, int n_in,
                              void* d_out, int out_size, void* d_ws, size_t ws_size,
                              hipStream_t stream) {
    const float* x  = (const float*)d_in[0];   // (16,512,64,64)
    const float* w  = (const float*)d_in[1];   // (16,512)
    const float* cw = (const float*)d_in[2];   // (512,512,3,3)
    const float* lw = (const float*)d_in[3];   // (512,512)
    const float* lb = (const float*)d_in[4];   // (512,)
    float* out = (float*)d_out;

    char* ws = (char*)d_ws;
    float*    style = (float*)(ws + WS_STYLE);
    float*    invd  = (float*)(ws + WS_INVD);
    float*    wsq   = (float*)(ws + WS_WSQ);
    ushort_t* Aw    = (ushort_t*)(ws + WS_AW);
    ushort_t* Xp    = (ushort_t*)(ws + WS_XP);

    compute_style<<<2048, 256, 0, stream>>>(w, lw, lb, style);
    prep_weights<<<1024, 256, 0, stream>>>(cw, Aw, wsq);
    compute_invd<<<2048, 256, 0, stream>>>(wsq, style, invd);
    dim3 gz(260, 16);
    zero_border<<<gz, 64, 0, stream>>>(Xp);
    dim3 g4(64, 8, 16);
    modulate_transpose<<<g4, 256, 0, stream>>>(x, style, Xp);
    conv_gemm<<<512, 512, 0, stream>>>(Aw, Xp, invd, out);
}

// Round 2
// 481.644 us; speedup vs baseline: 1.0423x; 1.0423x over previous
//
#include <hip/hip_runtime.h>

typedef unsigned short ushort_t;
typedef unsigned int uint_t;
typedef __bf16 bf16x8 __attribute__((ext_vector_type(8)));
typedef float float4v __attribute__((ext_vector_type(4)));
typedef uint_t uint4v __attribute__((ext_vector_type(4)));

#define EPS 1e-6f

// Workspace layout (bytes)
#define WS_STYLE   0            // 16*512 f32 = 32 KB
#define WS_INVD    32768        // 16*512 f32 = 32 KB
#define WS_WSQ     65536        // 512*512 f32 = 1 MB
#define WS_AW      1114112      // 512*4608 bf16 = 4,718,592 B
#define WS_XP      6291456      // 16*66*66*512 bf16 = 71,368,704 B

__device__ __forceinline__ ushort_t f2bf(float v) {
    union { float f; uint_t u; } c; c.f = v;
    uint_t u = c.u;
    u += 0x7fffu + ((u >> 16) & 1u);   // round-to-nearest-even
    return (ushort_t)(u >> 16);
}

__device__ __forceinline__ void gload_lds16(const void* g, void* l) {
    __builtin_amdgcn_global_load_lds(
        (const __attribute__((address_space(1))) uint_t*)g,
        (__attribute__((address_space(3))) uint_t*)l, 16, 0, 0);
}

// ---------------- L1 (fused): style GEMV + weight cast/permute ----------------
// blk < 2048:   style[b][o] = w[b,:] . lw[o,:] + lb[o]
// blk >= 2048:  Aw[o][k], k = iblk*576 + t*64 + (i&63)  (channel-block-outer, tap-inner)
//               wsq[o][i] = sum_t cw[o][i][t]^2
__global__ void prep_fused1(const float* __restrict__ w, const float* __restrict__ lw,
                            const float* __restrict__ lb, const float* __restrict__ cw,
                            float* __restrict__ style, ushort_t* __restrict__ Aw,
                            float* __restrict__ wsq) {
    int blk = blockIdx.x;
    if (blk < 2048) {
        int gw = blk * 4 + (threadIdx.x >> 6);   // 0..8191
        int lane = threadIdx.x & 63;
        int b = gw >> 9, o = gw & 511;
        float s = 0.f;
#pragma unroll
        for (int j = 0; j < 8; ++j) {
            int d = j * 64 + lane;
            s += w[b * 512 + d] * lw[o * 512 + d];
        }
#pragma unroll
        for (int off = 32; off; off >>= 1) s += __shfl_down(s, off);
        if (lane == 0) style[gw] = s + lb[o];
    } else {
        int id = (blk - 2048) * 256 + threadIdx.x;   // o*512 + i
        int o = id >> 9, i = id & 511;
        const float* p = cw + (size_t)id * 9;
        size_t base = (size_t)o * 4608 + (size_t)(i >> 6) * 576 + (i & 63);
        float s = 0.f;
#pragma unroll
        for (int t = 0; t < 9; ++t) {
            float v = p[t];
            s += v * v;
            Aw[base + t * 64] = f2bf(v);
        }
        wsq[id] = s;
    }
}

// ---------------- L2 (fused): inv_denom + border zero + modulate/transpose ----------------
__global__ void prep_fused2(const float* __restrict__ wsq, const float* __restrict__ style,
                            float* __restrict__ invd, const float* __restrict__ x,
                            ushort_t* __restrict__ Xp) {
    __shared__ ushort_t tile[64][65];   // modulate branch only
    int blk = blockIdx.x;
    if (blk < 2048) {
        // invd[b][o] = rsqrt(sum_i wsq[o][i]*style[b][i]^2 + eps)
        int gw = blk * 4 + (threadIdx.x >> 6);
        int lane = threadIdx.x & 63;
        int b = gw >> 9, o = gw & 511;
        float s = 0.f;
#pragma unroll
        for (int j = 0; j < 8; ++j) {
            int d = j * 64 + lane;
            float st = style[b * 512 + d];
            s += wsq[o * 512 + d] * st * st;
        }
#pragma unroll
        for (int off = 32; off; off >>= 1) s += __shfl_down(s, off);
        if (lane == 0) invd[gw] = rsqrtf(s + EPS);
    } else if (blk < 3088) {
        // zero the 1-px padding border of Xp (NHWC, 66x66); 4 border-pixels/block
        int j = (blk - 2048) * 4 + (threadIdx.x >> 6);   // 0..4159
        int lane = threadIdx.x & 63;
        int b = j / 260, bp = j - b * 260;
        int py, px;
        if (bp < 66)       { py = 0;        px = bp; }
        else if (bp < 132) { py = 65;       px = bp - 66; }
        else if (bp < 196) { py = bp - 131; px = 0; }
        else               { py = bp - 195; px = 65; }
        size_t pix = ((size_t)b * 66 + py) * 66 + px;
        ((uint4v*)(Xp + pix * 512))[lane] = (uint4v){0, 0, 0, 0};
    } else {
        // Xp[b][y+1][x+1][i] = bf16(x[b][i][y][x] * style[b][i])  (NHWC interior)
        int mb = blk - 3088;          // 0..8191
        int y = mb & 63;
        int chunk = mb >> 6;          // 0..127
        int i0 = (chunk & 7) * 64;
        int b = chunk >> 3;
        int tid = threadIdx.x;
        int sub = tid >> 6;           // 0..3 (wave)
        int lane = tid & 63;          // x position
#pragma unroll
        for (int pass = 0; pass < 16; ++pass) {
            int ir = pass * 4 + sub;
            float s = style[b * 512 + i0 + ir];
            float v = x[(((size_t)b * 512 + i0 + ir) * 64 + y) * 64 + lane] * s;
            tile[ir][lane] = f2bf(v);
        }
        __syncthreads();
        size_t rowbase = ((size_t)b * 66 + (y + 1)) * 66 + 1;
#pragma unroll
        for (int pass = 0; pass < 2; ++pass) {
            int idx = pass * 256 + tid;
            int xx = idx >> 3;        // 0..63
            int ch8 = idx & 7;        // 8-channel chunk
            ushort_t v[8];
#pragma unroll
            for (int j = 0; j < 8; ++j) v[j] = tile[ch8 * 8 + j][xx];
            *(uint4v*)(Xp + (rowbase + xx) * 512 + i0 + ch8 * 8) = *(uint4v*)v;
        }
    }
}

// ---------------- Main implicit-GEMM conv: per batch M=512, N=4096, K=4608 ----------------
// 256x256 tile, BK=64, 512 threads (8 waves, 2M x 4N), per-wave 128x64 output.
// K order is channel-block-outer, tap-inner (kt = iblk*9 + t): each 64-ch B slab is
// re-read 9x in CONSECUTIVE K-tiles -> L2-resident reuse (was tap-outer: reuse
// distance of 8 K-tiles -> 608 MB HBM fetch vs ~110 MB ideal).
// XCD swizzle: concurrent 32 blocks of an XCD = both o-tiles x 16 p-tiles of ONE
// batch (live B = 4.5 MB ~ L2/XCD); each XCD owns 2 batches sequentially.
// Pipeline: stages run 2 K-tiles ahead; counted s_waitcnt vmcnt(8) (never 0 in the
// main loop) keeps next K-tile's global_load_lds in flight across both barriers.
__global__ __launch_bounds__(512, 2) void conv_gemm(const ushort_t* __restrict__ Aw,
                                                    const ushort_t* __restrict__ Xp,
                                                    const float* __restrict__ invd,
                                                    float* __restrict__ out) {
    __shared__ ushort_t lds[2][32768];   // per buf: A [0,32KB), B [32KB,64KB)

    const int tid  = threadIdx.x;
    const int lane = tid & 63;
    const int wv   = tid >> 6;      // 0..7
    const int wm   = wv >> 2;       // 0..1  (M half)
    const int wn   = wv & 3;        // 0..3  (N quarter)
    const int l15  = lane & 15;
    const int quad = lane >> 4;

    // XCD-aware bijective remap: bid -> xcd = bid&7, chunk ci = bid>>3 (0..63).
    // First 32 chunks of each XCD = batch xcd*2 (all o-tiles x p-tiles), next 32 =
    // batch xcd*2+1. With 1 block/CU and 32 CUs/XCD, the concurrent set is one batch.
    const int bid = blockIdx.x;
    const int xcd = bid & 7;
    const int ci  = bid >> 3;
    const int b   = xcd * 2 + (ci >> 5);
    const int ot  = (ci >> 4) & 1;
    const int pxt = ci & 15;
    const int o0  = ot * 256;
    const int p0  = pxt * 256;

    // ---- staging addresses: thread tid covers granule q = s*512+tid, s=0..3 ----
    // row = s*64 + (tid>>3); stored slot = tid&7; source granule g = slot ^ (row&7)
    const int tr  = tid >> 3;                           // 0..63
    const int gsw = (((tid & 7) ^ (tr & 7)) << 4);      // source granule byte offset
    const char* Ab = (const char*)Aw;
    const char* Xb = (const char*)Xp;
    const char* aga[4];
    const char* bga[4];
#pragma unroll
    for (int s = 0; s < 4; ++s) {
        int row = s * 64 + tr;                          // 0..255 within tile
        aga[s] = Ab + (size_t)(o0 + row) * 9216 + gsw;
        int py0 = pxt * 4 + s;                          // image row of this stage's pixels
        bga[s] = Xb + ((size_t)(b * 66 + py0) * 66 + tr) * 1024 + gsw;
    }
    const int lds_wv = wv * 1024;                       // wave-uniform byte base within stage

    // ---- read-side (frag) addresses ----
    const int sw0 = ((quad ^ (l15 & 7)) << 4);          // k-slice 0 granule slot
    const int sw1 = (((4 + quad) ^ (l15 & 7)) << 4);    // k-slice 1
    const int aoffs = (wm * 128 + l15) * 128;           // A row byte offset (+ mi*2048)
    const int boffs = 32768 + (wn * 64 + l15) * 128;    // B row byte offset (+ ni*2048)

    float4v acc[8][4] = {};

    auto stage = [&](int kt) {
        const int parity = kt & 1;
        const long aoff = (long)kt * 128;               // A is contiguous in new k order
        const int iblk = (kt * 7282) >> 16;             // floor(kt/9), kt < 72
        const int t = kt - iblk * 9;                    // tap 0..8
        const int dh = t / 3, dw = t - dh * 3;
        const long boff = (long)(dh * 66 + dw) * 1024 + (long)iblk * 128;
        char* la = (char*)&lds[parity][0]     + lds_wv;
        char* lb = (char*)&lds[parity][16384] + lds_wv;
#pragma unroll
        for (int s = 0; s < 4; ++s) {
            gload_lds16(aga[s] + aoff, la + s * 8192);
            gload_lds16(bga[s] + boff, lb + s * 8192);
        }
    };

    // prologue: fill the pipe 2 K-tiles deep
    stage(0);
    stage(1);

#pragma unroll 1
    for (int kt = 0; kt < 72; ++kt) {
        if (kt < 71) { asm volatile("s_waitcnt vmcnt(8)" ::: "memory"); }
        else         { asm volatile("s_waitcnt vmcnt(0)" ::: "memory"); }
        __builtin_amdgcn_s_barrier();

        const char* base = (const char*)&lds[kt & 1][0];
        bf16x8 a0[8], a1[8], b0[4], b1[4];
#pragma unroll
        for (int mi = 0; mi < 8; ++mi)
            a0[mi] = *(const bf16x8*)(base + aoffs + mi * 2048 + sw0);
#pragma unroll
        for (int ni = 0; ni < 4; ++ni)
            b0[ni] = *(const bf16x8*)(base + boffs + ni * 2048 + sw0);

        __builtin_amdgcn_s_setprio(1);
#pragma unroll
        for (int mi = 0; mi < 8; ++mi)
#pragma unroll
            for (int ni = 0; ni < 4; ++ni)
                acc[mi][ni] = __builtin_amdgcn_mfma_f32_16x16x32_bf16(a0[mi], b0[ni], acc[mi][ni], 0, 0, 0);
        __builtin_amdgcn_s_setprio(0);

#pragma unroll
        for (int mi = 0; mi < 8; ++mi)
            a1[mi] = *(const bf16x8*)(base + aoffs + mi * 2048 + sw1);
#pragma unroll
        for (int ni = 0; ni < 4; ++ni)
            b1[ni] = *(const bf16x8*)(base + boffs + ni * 2048 + sw1);

        asm volatile("s_waitcnt lgkmcnt(0)" ::: "memory");   // ks1 frags in VGPRs
        __builtin_amdgcn_s_barrier();                        // all reads of buf[kt&1] done

        if (kt < 70) stage(kt + 2);                          // overwrite just-freed buffer

        __builtin_amdgcn_s_setprio(1);
#pragma unroll
        for (int mi = 0; mi < 8; ++mi)
#pragma unroll
            for (int ni = 0; ni < 4; ++ni)
                acc[mi][ni] = __builtin_amdgcn_mfma_f32_16x16x32_bf16(a1[mi], b1[ni], acc[mi][ni], 0, 0, 0);
        __builtin_amdgcn_s_setprio(0);
    }

    // epilogue: out[b][o][p] = acc * inv_denom[b][o]
    const float* invb = invd + b * 512 + o0 + wm * 128;
    float* outb = out + ((size_t)b * 512 + o0 + wm * 128) * 4096 + p0 + wn * 64;
#pragma unroll
    for (int mi = 0; mi < 8; ++mi) {
#pragma unroll
        for (int r = 0; r < 4; ++r) {
            int m = mi * 16 + quad * 4 + r;
            float d = invb[m];
#pragma unroll
            for (int ni = 0; ni < 4; ++ni) {
                int n = ni * 16 + l15;
                outb[(size_t)m * 4096 + n] = acc[mi][ni][r] * d;
            }
        }
    }
}

extern "C" void kernel_launch(void* const* d_in, const int* in_sizes, int n_in,
                              void* d_out, int out_size, void* d_ws, size_t ws_size,
                              hipStream_t stream) {
    const float* x  = (const float*)d_in[0];   // (16,512,64,64)
    const float* w  = (const float*)d_in[1];   // (16,512)
    const float* cw = (const float*)d_in[2];   // (512,512,3,3)
    const float* lw = (const float*)d_in[3];   // (512,512)
    const float* lb = (const float*)d_in[4];   // (512,)
    float* out = (float*)d_out;

    char* ws = (char*)d_ws;
    float*    style = (float*)(ws + WS_STYLE);
    float*    invd  = (float*)(ws + WS_INVD);
    float*    wsq   = (float*)(ws + WS_WSQ);
    ushort_t* Aw    = (ushort_t*)(ws + WS_AW);
    ushort_t* Xp    = (ushort_t*)(ws + WS_XP);

    prep_fused1<<<3072, 256, 0, stream>>>(w, lw, lb, cw, style, Aw, wsq);
    prep_fused2<<<11280, 256, 0, stream>>>(wsq, style, invd, x, Xp);
    conv_gemm<<<512, 512, 0, stream>>>(Aw, Xp, invd, out);
}

// Round 3
// 471.443 us; speedup vs baseline: 1.0649x; 1.0216x over previous
//
#include <hip/hip_runtime.h>

typedef unsigned short ushort_t;
typedef unsigned int uint_t;
typedef __bf16 bf16x8 __attribute__((ext_vector_type(8)));
typedef float float4v __attribute__((ext_vector_type(4)));
typedef uint_t uint4v __attribute__((ext_vector_type(4)));
typedef uint_t uint2v __attribute__((ext_vector_type(2)));

#define EPS 1e-6f

// Workspace layout (bytes)
#define WS_STYLE   0            // 16*512 f32 = 32 KB
#define WS_INVD    32768        // 16*512 f32 = 32 KB
#define WS_WSQ     65536        // 512*512 f32 = 1 MB
#define WS_AW      1114112      // 512*4608 bf16 = 4,718,592 B
#define WS_XP      6291456      // 16*66*66*512 bf16 = 71,368,704 B

__device__ __forceinline__ ushort_t f2bf(float v) {
    union { float f; uint_t u; } c; c.f = v;
    uint_t u = c.u;
    u += 0x7fffu + ((u >> 16) & 1u);   // round-to-nearest-even
    return (ushort_t)(u >> 16);
}

__device__ __forceinline__ void gload_lds16(const void* g, void* l) {
    __builtin_amdgcn_global_load_lds(
        (const __attribute__((address_space(1))) uint_t*)g,
        (__attribute__((address_space(3))) uint_t*)l, 16, 0, 0);
}

// ---------------- L1 (fused): style GEMV + weight cast/permute ----------------
__global__ void prep_fused1(const float* __restrict__ w, const float* __restrict__ lw,
                            const float* __restrict__ lb, const float* __restrict__ cw,
                            float* __restrict__ style, ushort_t* __restrict__ Aw,
                            float* __restrict__ wsq) {
    int blk = blockIdx.x;
    if (blk < 2048) {
        int gw = blk * 4 + (threadIdx.x >> 6);   // 0..8191
        int lane = threadIdx.x & 63;
        int b = gw >> 9, o = gw & 511;
        float s = 0.f;
#pragma unroll
        for (int j = 0; j < 8; ++j) {
            int d = j * 64 + lane;
            s += w[b * 512 + d] * lw[o * 512 + d];
        }
#pragma unroll
        for (int off = 32; off; off >>= 1) s += __shfl_down(s, off);
        if (lane == 0) style[gw] = s + lb[o];
    } else {
        int id = (blk - 2048) * 256 + threadIdx.x;   // o*512 + i
        int o = id >> 9, i = id & 511;
        const float* p = cw + (size_t)id * 9;
        size_t base = (size_t)o * 4608 + (size_t)(i >> 6) * 576 + (i & 63);
        float s = 0.f;
#pragma unroll
        for (int t = 0; t < 9; ++t) {
            float v = p[t];
            s += v * v;
            Aw[base + t * 64] = f2bf(v);
        }
        wsq[id] = s;
    }
}

// ---------------- L2 (fused): inv_denom + border zero + modulate/transpose ----------------
__global__ void prep_fused2(const float* __restrict__ wsq, const float* __restrict__ style,
                            float* __restrict__ invd, const float* __restrict__ x,
                            ushort_t* __restrict__ Xp) {
    __shared__ ushort_t tile[64][66];   // modulate branch only (stride 66: even, odd-dword)
    int blk = blockIdx.x;
    if (blk < 2048) {
        // invd[b][o] = rsqrt(sum_i wsq[o][i]*style[b][i]^2 + eps)
        int gw = blk * 4 + (threadIdx.x >> 6);
        int lane = threadIdx.x & 63;
        int b = gw >> 9, o = gw & 511;
        float s = 0.f;
#pragma unroll
        for (int j = 0; j < 8; ++j) {
            int d = j * 64 + lane;
            float st = style[b * 512 + d];
            s += wsq[o * 512 + d] * st * st;
        }
#pragma unroll
        for (int off = 32; off; off >>= 1) s += __shfl_down(s, off);
        if (lane == 0) invd[gw] = rsqrtf(s + EPS);
    } else if (blk < 3088) {
        // zero the 1-px padding border of Xp (NHWC, 66x66); 4 border-pixels/block
        int j = (blk - 2048) * 4 + (threadIdx.x >> 6);   // 0..4159
        int lane = threadIdx.x & 63;
        int b = j / 260, bp = j - b * 260;
        int py, px;
        if (bp < 66)       { py = 0;        px = bp; }
        else if (bp < 132) { py = 65;       px = bp - 66; }
        else if (bp < 196) { py = bp - 131; px = 0; }
        else               { py = bp - 195; px = 65; }
        size_t pix = ((size_t)b * 66 + py) * 66 + px;
        ((uint4v*)(Xp + pix * 512))[lane] = (uint4v){0, 0, 0, 0};
    } else {
        // Xp[b][y+1][x+1][i] = bf16(x[b][i][y][x] * style[b][i])  (NHWC interior)
        // float4 loads: 16 B/lane (G13), 4 passes instead of 16 scalar.
        int mb = blk - 3088;          // 0..8191
        int y = mb & 63;
        int chunk = mb >> 6;          // 0..127
        int i0 = (chunk & 7) * 64;
        int b = chunk >> 3;
        int tid = threadIdx.x;
        int ch = tid >> 2;            // 0..63 channel within tile
        int xq = tid & 3;             // x-quarter slot
        float s = style[b * 512 + i0 + ch];
        const float* xrow = x + (((size_t)b * 512 + i0 + ch) * 64 + y) * 64;
#pragma unroll
        for (int pass = 0; pass < 4; ++pass) {
            int x0 = pass * 16 + xq * 4;
            float4v v = *(const float4v*)(xrow + x0);
            ushort_t u[4];
#pragma unroll
            for (int j = 0; j < 4; ++j) u[j] = f2bf(v[j] * s);
            *(uint2v*)(&tile[ch][x0]) = *(const uint2v*)u;
        }
        __syncthreads();
        size_t rowbase = ((size_t)b * 66 + (y + 1)) * 66 + 1;
#pragma unroll
        for (int pass = 0; pass < 2; ++pass) {
            int idx = pass * 256 + tid;
            int xx = idx >> 3;        // 0..63
            int ch8 = idx & 7;        // 8-channel chunk
            ushort_t v[8];
#pragma unroll
            for (int j = 0; j < 8; ++j) v[j] = tile[ch8 * 8 + j][xx];
            *(uint4v*)(Xp + (rowbase + xx) * 512 + i0 + ch8 * 8) = *(uint4v*)v;
        }
    }
}

// ---------------- Main implicit-GEMM conv: per batch M=512, N=4096, K=4608 ----------------
// 256x256 tile, BK=64, 512 threads (8 waves, 2M x 4N), per-wave 128x64 output.
// Cross-barrier read pipelining, ONE barrier per K-tile:
//   Region A: ds_read ks1(kt) frags (12) interleaved with 32 MFMA on preloaded ks0;
//   lgkmcnt(0) (all buf[kt&1] reads done) + vmcnt(0) (stage(kt+1) landed, issued a
//   full K-tile earlier) + s_barrier;
//   Region B: ds_read ks0(kt+1) from the OTHER buffer (no WAR with the stage) ||
//   issue stage(kt+2) into buf[kt&1] || 32 MFMA on ks1 (zero read-wait).
// So LDS reads flow under MFMAs in BOTH windows instead of alternating.
// K order channel-block-outer/tap-inner (L2-resident B reuse, r1); XCD remap: one
// batch concurrent per XCD (r1). LDS granule-slot XOR swizzle as before (0 conflicts).
__global__ __launch_bounds__(512, 2) void conv_gemm(const ushort_t* __restrict__ Aw,
                                                    const ushort_t* __restrict__ Xp,
                                                    const float* __restrict__ invd,
                                                    float* __restrict__ out) {
    __shared__ ushort_t lds[2][32768];   // per buf: A [0,32KB), B [32KB,64KB)

    const int tid  = threadIdx.x;
    const int lane = tid & 63;
    const int wv   = tid >> 6;      // 0..7
    const int wm   = wv >> 2;       // 0..1  (M half)
    const int wn   = wv & 3;        // 0..3  (N quarter)
    const int l15  = lane & 15;
    const int quad = lane >> 4;

    // XCD-aware bijective remap: one batch concurrent per XCD.
    const int bid = blockIdx.x;
    const int xcd = bid & 7;
    const int ci  = bid >> 3;
    const int b   = xcd * 2 + (ci >> 5);
    const int ot  = (ci >> 4) & 1;
    const int pxt = ci & 15;
    const int o0  = ot * 256;
    const int p0  = pxt * 256;

    // staging: thread tid covers granule q = s*512+tid; row = s*64+(tid>>3),
    // stored slot = tid&7, source granule = slot ^ (row&7)
    const int tr  = tid >> 3;                           // 0..63
    const int gsw = (((tid & 7) ^ (tr & 7)) << 4);
    const char* aga0 = (const char*)Aw + (size_t)(o0 + tr) * 9216 + gsw;
    const char* bga0 = (const char*)Xp + ((size_t)(b * 66 + pxt * 4) * 66 + tr) * 1024 + gsw;
    const int lds_wv = wv * 1024;

    // read-side (frag) addresses
    const int sw0 = ((quad ^ (l15 & 7)) << 4);
    const int sw1 = (((4 + quad) ^ (l15 & 7)) << 4);
    const int aoffs = (wm * 128 + l15) * 128;           // + mi*2048
    const int boffs = 32768 + (wn * 64 + l15) * 128;    // + ni*2048

    float4v acc[8][4] = {};
    bf16x8 a0[8], b0[4], a1[8], b1[4];

    auto stage = [&](int kt2) {
        const int parity = kt2 & 1;
        const long aoff = (long)kt2 * 128;
        const int iblk = (kt2 * 7282) >> 16;            // floor(kt2/9)
        const int t = kt2 - iblk * 9;
        const int dh = t / 3, dw = t - dh * 3;
        const long boff = (long)(dh * 66 + dw) * 1024 + (long)iblk * 128;
        char* la = (char*)&lds[parity][0]     + lds_wv;
        char* lb = (char*)&lds[parity][16384] + lds_wv;
#pragma unroll
        for (int s = 0; s < 4; ++s) {
            gload_lds16(aga0 + (size_t)s * 589824 + aoff, la + s * 8192);
            gload_lds16(bga0 + (size_t)s * 67584  + boff, lb + s * 8192);
        }
    };

    // prologue: prime 2 K-tiles, certify tile 0, preload ks0(0) frags
    stage(0);
    stage(1);
    asm volatile("s_waitcnt vmcnt(8)" ::: "memory");
    __builtin_amdgcn_s_barrier();
    {
        const char* base = (const char*)&lds[0][0];
#pragma unroll
        for (int ni = 0; ni < 4; ++ni) b0[ni] = *(const bf16x8*)(base + boffs + ni * 2048 + sw0);
#pragma unroll
        for (int mi = 0; mi < 8; ++mi) a0[mi] = *(const bf16x8*)(base + aoffs + mi * 2048 + sw0);
    }

#pragma unroll 1
    for (int kt = 0; kt < 72; ++kt) {
        const char* cbase = (const char*)&lds[kt & 1][0];

        // Region A: ks1 reads flow under h0 MFMAs
#pragma unroll
        for (int ni = 0; ni < 4; ++ni) b1[ni] = *(const bf16x8*)(cbase + boffs + ni * 2048 + sw1);
#pragma unroll
        for (int mi = 0; mi < 8; ++mi) a1[mi] = *(const bf16x8*)(cbase + aoffs + mi * 2048 + sw1);

        __builtin_amdgcn_s_setprio(1);
#pragma unroll
        for (int mi = 0; mi < 8; ++mi)
#pragma unroll
            for (int ni = 0; ni < 4; ++ni)
                acc[mi][ni] = __builtin_amdgcn_mfma_f32_16x16x32_bf16(a0[mi], b0[ni], acc[mi][ni], 0, 0, 0);
        __builtin_amdgcn_s_setprio(0);

        asm volatile("s_waitcnt lgkmcnt(0)" ::: "memory");   // all my buf[kt&1] reads done
        asm volatile("s_waitcnt vmcnt(0)" ::: "memory");     // stage(kt+1) landed (1-tile slack)
        __builtin_amdgcn_s_barrier();

        // Region B: next-tile ks0 reads (other buffer) || stage || h1 MFMAs
        if (kt < 71) {
            const char* nbase = (const char*)&lds[(kt + 1) & 1][0];
#pragma unroll
            for (int ni = 0; ni < 4; ++ni) b0[ni] = *(const bf16x8*)(nbase + boffs + ni * 2048 + sw0);
#pragma unroll
            for (int mi = 0; mi < 8; ++mi) a0[mi] = *(const bf16x8*)(nbase + aoffs + mi * 2048 + sw0);
        }
        if (kt < 70) stage(kt + 2);

        __builtin_amdgcn_s_setprio(1);
#pragma unroll
        for (int mi = 0; mi < 8; ++mi)
#pragma unroll
            for (int ni = 0; ni < 4; ++ni)
                acc[mi][ni] = __builtin_amdgcn_mfma_f32_16x16x32_bf16(a1[mi], b1[ni], acc[mi][ni], 0, 0, 0);
        __builtin_amdgcn_s_setprio(0);
    }

    // epilogue: out[b][o][p] = acc * inv_denom[b][o]
    const float* invb = invd + b * 512 + o0 + wm * 128;
    float* outb = out + ((size_t)b * 512 + o0 + wm * 128) * 4096 + p0 + wn * 64;
#pragma unroll
    for (int mi = 0; mi < 8; ++mi) {
#pragma unroll
        for (int r = 0; r < 4; ++r) {
            int m = mi * 16 + quad * 4 + r;
            float d = invb[m];
#pragma unroll
            for (int ni = 0; ni < 4; ++ni) {
                int n = ni * 16 + l15;
                outb[(size_t)m * 4096 + n] = acc[mi][ni][r] * d;
            }
        }
    }
}

extern "C" void kernel_launch(void* const* d_in, const int* in_sizes, int n_in,
                              void* d_out, int out_size, void* d_ws, size_t ws_size,
                              hipStream_t stream) {
    const float* x  = (const float*)d_in[0];   // (16,512,64,64)
    const float* w  = (const float*)d_in[1];   // (16,512)
    const float* cw = (const float*)d_in[2];   // (512,512,3,3)
    const float* lw = (const float*)d_in[3];   // (512,512)
    const float* lb = (const float*)d_in[4];   // (512,)
    float* out = (float*)d_out;

    char* ws = (char*)d_ws;
    float*    style = (float*)(ws + WS_STYLE);
    float*    invd  = (float*)(ws + WS_INVD);
    float*    wsq   = (float*)(ws + WS_WSQ);
    ushort_t* Aw    = (ushort_t*)(ws + WS_AW);
    ushort_t* Xp    = (ushort_t*)(ws + WS_XP);

    prep_fused1<<<3072, 256, 0, stream>>>(w, lw, lb, cw, style, Aw, wsq);
    prep_fused2<<<11280, 256, 0, stream>>>(wsq, style, invd, x, Xp);
    conv_gemm<<<512, 512, 0, stream>>>(Aw, Xp, invd, out);
}